// Round 1
// baseline (221.495 us; speedup 1.0000x reference)
//
#include <hip/hip_runtime.h>

// ViT cls-token-only forward. B=16, C=8, D=511, DIM=2048, SEQ=512, NH=16.
// q = (cls+pos0) @ Wq + bq (batch-independent); r[h] = SCALE * Wk_h @ q_h;
// scores[b,h,j] = tok[b,j].r[h]; softmax; u[b,h] = sum_j p tok[b,j];
// ao = u @ Wv + bv; out = ao @ proj_w + proj_b.
//
// R9: dispatch-count + k5-traffic round.
//  - k0 removed. Zeroing (G+AO+out, 0.25 MB) folded into k1. posT dropped.
//  - k1 writes q PARTIALS per 32-d chunk (plain stores, no atomics, no zero
//    dependency); k2 sums the 64 partials while staging q into LDS.
//  - k3 writes scores to 4 per-ks partial buffers (plain stores, no atomics,
//    no SC zeroing); k5 sums the 4 partials inside its fused softmax.
//  - k5 rewritten: tok tile (32 j x 64 d) staged to LDS with coalesced
//    float4 reads of x and pos (256-B segments, line-exclusive per block ->
//    x fetched exactly once), bf16 hi/lo conversion during staging,
//    double-buffered. Replaces per-lane 4-B stride-1KB column loads that
//    over-fetched ~4x across XCD L2s, and removes the need for posT.
//  - Dispatches 7 -> 6.

#define BB   16
#define CC   8
#define DD   511
#define DIM  2048
#define SEQ  512
#define NH   16
#define HD   128
#define W3   6144
#define SCALE 0.08838834764831845f

// workspace layout (float offsets)
#define QP_OFF  0            // 64*2048 = 131072 q partials (plain)
#define G_OFF   131072       // 16      atomic gamma    (zeroed by k1)
#define AO_OFF  131088       // 32768   atomic ao       (zeroed by k1)
#define SCP_OFF 163856       // 4*131072 score partials (plain)
#define SCPSZ   131072
#define R_OFF   688144       // 32768   fp32 r (plain)
#define RB_OFF  720912       // 32768 float slots = 65536 shorts: r bf16 hi/lo
#define U_OFF   753680       // 524288  u (plain)
// total = 1,277,968 floats ~= 5.1 MB

#define PSTR 520
#define CJ   32              // k5 j-chunk rows
#define TSTR 68              // k5 tok LDS short-stride (pad vs 64)

typedef __attribute__((ext_vector_type(8))) short short8;
typedef __attribute__((ext_vector_type(4))) float floatx4;

static __device__ inline short bf_hi(float f) {
  return (short)(__float_as_uint(f) >> 16);          // truncate to bf16
}
static __device__ inline float bf_hif(float f) {
  return __uint_as_float(__float_as_uint(f) & 0xffff0000u);
}

// K1: q partials + zeroing. qpart[dc][n] = sum_{d in chunk} t0[d]*Wq[d][n]
// (+bias at dc==0). Also zeroes G+AO (32784 floats) and out (32768).
// grid (8 ntile, 64 dchunk) x 256.
__global__ __launch_bounds__(256) void k1_q(
    const float* __restrict__ pos, const float* __restrict__ cls,
    const float* __restrict__ qkv_w, const float* __restrict__ qkv_b,
    float* __restrict__ ws, float* __restrict__ out) {
  int n  = blockIdx.x * 256 + threadIdx.x;
  int dc = blockIdx.y;
  int tid = (blockIdx.x + blockIdx.y * 8) * 256 + threadIdx.x;  // 0..131071
  if (tid < 32784) ws[G_OFF + tid] = 0.f;        // G + AO contiguous
  if (tid < BB * DIM) out[tid] = 0.f;
  int d0 = dc * 32;
  float acc = (dc == 0) ? qkv_b[n] : 0.f;
#pragma unroll 8
  for (int d = d0; d < d0 + 32; ++d) {
    float t0 = cls[d] + pos[d];           // uniform -> scalar load
    acc += t0 * qkv_w[(size_t)d * W3 + n];
  }
  ws[QP_OFF + dc * DIM + n] = acc;
}

// K2: r[h][d] = SCALE * (Wk[d, h-slice] . q[h-slice]); q staged by summing
// the 64 k1 partials. Writes fp32 r, bf16 hi/lo, and atomic gamma[h].
// grid (16 dtile, 16 h), 128 thr.
__global__ __launch_bounds__(128) void k2_r(
    const float* __restrict__ qkv_w, const float* __restrict__ pos,
    const float* __restrict__ cls, float* __restrict__ ws) {
  __shared__ float qs[HD];
  int h = blockIdx.y;
  int d = blockIdx.x * 128 + threadIdx.x;
  float qa = 0.f;
#pragma unroll 8
  for (int c = 0; c < 64; ++c)
    qa += ws[QP_OFF + c * DIM + h * HD + threadIdx.x];
  qs[threadIdx.x] = qa;
  __syncthreads();
  const float4* w4 = reinterpret_cast<const float4*>(
      qkv_w + (size_t)d * W3 + DIM + h * HD);
  float acc = 0.f;
#pragma unroll 8
  for (int e4 = 0; e4 < 32; ++e4) {
    float4 w = w4[e4];
    acc += qs[e4*4+0]*w.x + qs[e4*4+1]*w.y + qs[e4*4+2]*w.z + qs[e4*4+3]*w.w;
  }
  float r = acc * SCALE;
  int i = h * DIM + d;
  ws[R_OFF + i] = r;
  short* rb = (short*)(ws + RB_OFF);
  rb[i] = bf_hi(r);
  rb[NH * DIM + i] = bf_hi(r - bf_hif(r));
  float g = (cls[d] + pos[d]) * r;        // fused gamma partial
  for (int m = 1; m < 64; m <<= 1) g += __shfl_xor(g, m, 64);
  if ((threadIdx.x & 63) == 0) atomicAdd(&ws[G_OFF + h], g);
}

// K3: scores[b,h,j] for j>=1 via MFMA, 3-term hi/lo. grid (8 jt2, 16 b, 4 ks),
// 256 thr = 4 waves; wave w owns j-tile jt = jt2*4+w. Plain store into the
// per-ks partial buffer (k5 sums the 4).
__global__ __launch_bounds__(256) void k3_scores_mfma(
    const float* __restrict__ x, const float* __restrict__ pos,
    float* __restrict__ ws) {
  int jt2 = blockIdx.x, b = blockIdx.y, ks = blockIdx.z;
  int t = threadIdx.x;
  int w = t >> 6, l = t & 63;
  int jt = jt2 * 4 + w;
  int m16 = l & 15, kg = l >> 4;
  int jrow = 1 + jt * 16 + m16;
  int jc = jrow < SEQ ? jrow : (SEQ - 1);   // clamp; jrow==512 masked at store
  const size_t xrow = (size_t)b * CC * DD * 256 + (size_t)(jc - 1) * 256;
  const short* rh = (const short*)(ws + RB_OFF);
  const short* rl = rh + NH * DIM;
  floatx4 acc = {0.f, 0.f, 0.f, 0.f};
#pragma unroll 2
  for (int kk = ks * 16; kk < ks * 16 + 16; ++kk) {
    int d0 = kk * 32 + kg * 8;
    int c = d0 >> 8, doff = d0 & 255;
    const float4* xp = reinterpret_cast<const float4*>(
        x + xrow + (size_t)c * DD * 256 + doff);
    const float4* pp = reinterpret_cast<const float4*>(
        pos + (size_t)jc * DIM + d0);
    float4 xa = xp[0], xb = xp[1];
    float4 pa = pp[0], pb = pp[1];
    float f[8] = {xa.x + pa.x, xa.y + pa.y, xa.z + pa.z, xa.w + pa.w,
                  xb.x + pb.x, xb.y + pb.y, xb.z + pb.z, xb.w + pb.w};
    short8 ahi, alo;
#pragma unroll
    for (int i = 0; i < 8; ++i) {
      ahi[i] = bf_hi(f[i]);
      alo[i] = bf_hi(f[i] - bf_hif(f[i]));   // f-hi exact, then truncate
    }
    short8 bhi = *reinterpret_cast<const short8*>(rh + m16 * DIM + d0);
    short8 blo = *reinterpret_cast<const short8*>(rl + m16 * DIM + d0);
    acc = __builtin_amdgcn_mfma_f32_16x16x32_bf16(ahi, bhi, acc, 0, 0, 0);
    acc = __builtin_amdgcn_mfma_f32_16x16x32_bf16(ahi, blo, acc, 0, 0, 0);
    acc = __builtin_amdgcn_mfma_f32_16x16x32_bf16(alo, bhi, acc, 0, 0, 0);
  }
  // C layout: col(h) = l&15, row(j) = (l>>4)*4 + reg  [m89-verified]
  int h = m16;
#pragma unroll
  for (int reg = 0; reg < 4; ++reg) {
    int row = kg * 4 + reg;
    int j = 1 + jt * 16 + row;
    if (j < SEQ)
      ws[SCP_OFF + (size_t)ks * SCPSZ + (size_t)(b * NH + h) * SEQ + j] =
          acc[reg];
  }
}

// K5: u[b] (16h x 2048d) = softmax(scores[b]) @ tok[b] via MFMA, 3-term
// hi/lo. Softmax fused into p-staging (sums 4 score partials + gamma).
// tok tile (32j x 64d) staged to LDS with coalesced float4 x/pos reads,
// converted to bf16 hi/lo once, double-buffered. grid (32 dt, 16 b).
__global__ __launch_bounds__(256) void k5_pv_mfma(
    const float* __restrict__ x, const float* __restrict__ pos,
    const float* __restrict__ cls, float* __restrict__ ws) {
  int dt = blockIdx.x, b = blockIdx.y, t = threadIdx.x;
  __shared__ __attribute__((aligned(16))) short phl[NH * PSTR];
  __shared__ __attribute__((aligned(16))) short pll[NH * PSTR];
  __shared__ short ths[2][CJ][TSTR];
  __shared__ short tls[2][CJ][TSTR];
  int w = t >> 6, l = t & 63;
  // ---- fused softmax: wave w handles rows h = w*4 .. w*4+3 ----
  for (int rr = 0; rr < 4; ++rr) {
    int h = w * 4 + rr;
    const float* sc0 = ws + SCP_OFF + (size_t)(b * NH + h) * SEQ;
    float gam = ws[G_OFF + h];
    float s[8];
#pragma unroll
    for (int i = 0; i < 8; ++i) {
      int j = i * 64 + l;
      s[i] = sc0[j] + sc0[SCPSZ + j] + sc0[2 * SCPSZ + j] + sc0[3 * SCPSZ + j];
    }
    if (l == 0) s[0] = gam;               // j=0 slot holds the cls score
    float mx = s[0];
#pragma unroll
    for (int i = 1; i < 8; ++i) mx = fmaxf(mx, s[i]);
    for (int m = 1; m < 64; m <<= 1) mx = fmaxf(mx, __shfl_xor(mx, m, 64));
    float e[8], sum = 0.f;
#pragma unroll
    for (int i = 0; i < 8; ++i) { e[i] = __expf(s[i] - mx); sum += e[i]; }
    for (int m = 1; m < 64; m <<= 1) sum += __shfl_xor(sum, m, 64);
    float inv = 1.f / sum;
#pragma unroll
    for (int i = 0; i < 8; ++i) {
      float p = e[i] * inv;
      int j = i * 64 + l;
      phl[h * PSTR + j] = bf_hi(p);
      pll[h * PSTR + j] = bf_hi(p - bf_hif(p));
    }
  }
  // ---- tok staging: 32j x 64d chunk, coalesced float4, bf16 hi/lo ----
  const size_t xb = (size_t)b * CC * DD * 256;
  auto stage = [&](int kk, int buf) {
#pragma unroll
    for (int rep = 0; rep < 2; ++rep) {
      int idx = rep * 256 + t;
      int jj = idx >> 4, f4 = idx & 15;   // 32 rows x 16 float4
      int j = kk * CJ + jj;
      int dbase = dt * 64 + f4 * 4;
      float4 pv = *reinterpret_cast<const float4*>(pos + (size_t)j * DIM + dbase);
      float4 xv;
      if (j == 0) {
        xv = *reinterpret_cast<const float4*>(cls + dbase);
      } else {
        int c = dbase >> 8, doff = dbase & 255;
        xv = *reinterpret_cast<const float4*>(
            x + xb + (size_t)c * DD * 256 + (size_t)(j - 1) * 256 + doff);
      }
      float f[4] = {xv.x + pv.x, xv.y + pv.y, xv.z + pv.z, xv.w + pv.w};
#pragma unroll
      for (int k = 0; k < 4; ++k) {
        ths[buf][jj][f4 * 4 + k] = bf_hi(f[k]);
        tls[buf][jj][f4 * 4 + k] = bf_hi(f[k] - bf_hif(f[k]));
      }
    }
  };
  stage(0, 0);
  // ---- MFMA main loop (double-buffered over 16 j-chunks) ----
  int m16 = l & 15, kq = l >> 4;
  int wd = w * 16 + m16;
  int dcol = dt * 64 + wd;
  const short8* pph = reinterpret_cast<const short8*>(&phl[m16 * PSTR]);
  const short8* ppl = reinterpret_cast<const short8*>(&pll[m16 * PSTR]);
  floatx4 acc = {0.f, 0.f, 0.f, 0.f};
  for (int kk = 0; kk < 16; ++kk) {
    __syncthreads();
    if (kk < 15) stage(kk + 1, (kk + 1) & 1);
    int buf = kk & 1;
    short8 thi, tlo;
#pragma unroll
    for (int i = 0; i < 8; ++i) {
      thi[i] = ths[buf][kq * 8 + i][wd];
      tlo[i] = tls[buf][kq * 8 + i][wd];
    }
    short8 phi = pph[kk * 4 + kq];
    short8 plo = ppl[kk * 4 + kq];
    acc = __builtin_amdgcn_mfma_f32_16x16x32_bf16(phi, thi, acc, 0, 0, 0);
    acc = __builtin_amdgcn_mfma_f32_16x16x32_bf16(phi, tlo, acc, 0, 0, 0);
    acc = __builtin_amdgcn_mfma_f32_16x16x32_bf16(plo, thi, acc, 0, 0, 0);
  }
  // C: col(d) = l&15, row(h) = kq*4+reg
  float* ub = ws + U_OFF + (size_t)b * NH * DIM + dcol;
#pragma unroll
  for (int reg = 0; reg < 4; ++reg)
    ub[(size_t)(kq * 4 + reg) * DIM] = acc[reg];
}

// K6: ao[b][m] += sum over 32-d chunk of u[b][h][d]*Wv[d][4096+m] (+bv),
// m = h*128+e. ALL 16 batches per block -> Wv read once. grid (8 nt, 64 dc).
__global__ __launch_bounds__(256) void k6_ao(
    const float* __restrict__ qkv_w, const float* __restrict__ qkv_b,
    float* __restrict__ ws) {
  int nt = blockIdx.x, dc = blockIdx.y, t = threadIdx.x;
  int m = nt * 256 + t;
  int h0 = nt * 2;                        // 2 heads per 256-wide n tile
  int d0 = dc * 32;
  __shared__ float us[2][32][20];         // stride 20: 16B-aligned rows
  for (int i = t; i < 2 * 32 * BB; i += 256) {
    int dd = i & 31, b = (i >> 5) & 15, hh = i >> 9;
    us[hh][dd][b] = ws[U_OFF + (size_t)(b * NH + h0 + hh) * DIM + d0 + dd];
  }
  __syncthreads();
  int hl = t >> 7;
  float acc[BB];
#pragma unroll
  for (int b = 0; b < BB; ++b) acc[b] = 0.f;
  const float* wcol = qkv_w + (size_t)d0 * W3 + 2 * DIM + m;
#pragma unroll 4
  for (int dd = 0; dd < 32; ++dd) {
    float w = wcol[(size_t)dd * W3];
    const float4* u4 = reinterpret_cast<const float4*>(&us[hl][dd][0]);
    float4 u0 = u4[0], u1 = u4[1], u2 = u4[2], u3 = u4[3];  // broadcast
    acc[0]  += u0.x * w; acc[1]  += u0.y * w; acc[2]  += u0.z * w; acc[3]  += u0.w * w;
    acc[4]  += u1.x * w; acc[5]  += u1.y * w; acc[6]  += u1.z * w; acc[7]  += u1.w * w;
    acc[8]  += u2.x * w; acc[9]  += u2.y * w; acc[10] += u2.z * w; acc[11] += u2.w * w;
    acc[12] += u3.x * w; acc[13] += u3.y * w; acc[14] += u3.z * w; acc[15] += u3.w * w;
  }
  float bias = (dc == 0) ? qkv_b[2 * DIM + m] : 0.f;
#pragma unroll
  for (int b = 0; b < BB; ++b)
    atomicAdd(&ws[AO_OFF + b * DIM + m], acc[b] + bias);
}

// K7: out[b][n] += sum over 32-m chunk of ao[b][m]*proj_w[m][n] (+pb).
// ALL 16 batches per block -> proj_w read once. grid (8 nt, 64 mc).
__global__ __launch_bounds__(256) void k7_out(
    const float* __restrict__ proj_w, const float* __restrict__ proj_b,
    const float* __restrict__ ws, float* __restrict__ out) {
  int nt = blockIdx.x, mc = blockIdx.y, t = threadIdx.x;
  int n = nt * 256 + t;
  int m0 = mc * 32;
  __shared__ float as[32][20];
  for (int i = t; i < 32 * BB; i += 256) {
    int mm = i & 31, b = i >> 5;
    as[mm][b] = ws[AO_OFF + b * DIM + m0 + mm];
  }
  __syncthreads();
  float acc[BB];
#pragma unroll
  for (int b = 0; b < BB; ++b) acc[b] = 0.f;
  const float* wcol = proj_w + (size_t)m0 * DIM + n;
#pragma unroll 4
  for (int mm = 0; mm < 32; ++mm) {
    float w = wcol[(size_t)mm * DIM];
    const float4* a4 = reinterpret_cast<const float4*>(&as[mm][0]);
    float4 a0 = a4[0], a1 = a4[1], a2 = a4[2], a3 = a4[3];  // broadcast
    acc[0]  += a0.x * w; acc[1]  += a0.y * w; acc[2]  += a0.z * w; acc[3]  += a0.w * w;
    acc[4]  += a1.x * w; acc[5]  += a1.y * w; acc[6]  += a1.z * w; acc[7]  += a1.w * w;
    acc[8]  += a2.x * w; acc[9]  += a2.y * w; acc[10] += a2.z * w; acc[11] += a2.w * w;
    acc[12] += a3.x * w; acc[13] += a3.y * w; acc[14] += a3.z * w; acc[15] += a3.w * w;
  }
  float bias = (mc == 0) ? proj_b[n] : 0.f;
#pragma unroll
  for (int b = 0; b < BB; ++b)
    atomicAdd(&out[b * DIM + n], acc[b] + bias);
}

extern "C" void kernel_launch(void* const* d_in, const int* in_sizes, int n_in,
                              void* d_out, int out_size, void* d_ws, size_t ws_size,
                              hipStream_t stream) {
  const float* x      = (const float*)d_in[0];
  const float* pos    = (const float*)d_in[1];
  const float* cls    = (const float*)d_in[2];
  const float* qkv_w  = (const float*)d_in[3];
  const float* qkv_b  = (const float*)d_in[4];
  const float* proj_w = (const float*)d_in[5];
  const float* proj_b = (const float*)d_in[6];
  float* ws  = (float*)d_ws;
  float* out = (float*)d_out;

  k1_q          <<<dim3(8, 64),     256, 0, stream>>>(pos, cls, qkv_w, qkv_b, ws, out);
  k2_r          <<<dim3(16, 16),    128, 0, stream>>>(qkv_w, pos, cls, ws);
  k3_scores_mfma<<<dim3(8, 16, 4),  256, 0, stream>>>(x, pos, ws);
  k5_pv_mfma    <<<dim3(32, 16),    256, 0, stream>>>(x, pos, cls, ws);
  k6_ao         <<<dim3(8, 64),     256, 0, stream>>>(qkv_w, qkv_b, ws);
  k7_out        <<<dim3(8, 64),     256, 0, stream>>>(proj_w, proj_b, ws, out);
}